// Round 3
// baseline (290.405 us; speedup 1.0000x reference)
//
#include <hip/hip_runtime.h>

#define TSEQ 512
#define NB   128
#define CDIM 384
#define HD   64

typedef _Float16 half8  __attribute__((ext_vector_type(8)));
typedef float    floatx4 __attribute__((ext_vector_type(4)));

__device__ __forceinline__ float bf2f(unsigned short u) {
    union { unsigned int i; float f; } v;
    v.i = ((unsigned int)u) << 16;
    return v.f;
}

// ---------------------------------------------------------------------------
// Kernel A: decide whether the inputs are bf16 or fp32.
// fp32 arrays viewed as 16-bit words: every even word is low-mantissa noise;
// ~43% of those decode (as bf16) to exponent >= 0x91 (|v| > 1e5). Genuine
// bf16 N(0,1) data never does. flag=1 -> inputs are fp32.
// ---------------------------------------------------------------------------
__global__ void detect_dtype(const unsigned short* __restrict__ x,
                             unsigned int* __restrict__ flag)
{
    __shared__ int cnt_s;
    if (threadIdx.x == 0) cnt_s = 0;
    __syncthreads();
    int c = 0;
    for (int i = threadIdx.x; i < 4096; i += 256) {
        int e = (x[i] >> 7) & 0xFF;
        if (e >= 0x91) ++c;
    }
    atomicAdd(&cnt_s, c);
    __syncthreads();
    if (threadIdx.x == 0) *flag = (cnt_s >= 16) ? 1u : 0u;
}

// ---------------------------------------------------------------------------
// Kernel B: repack the three 384x64 weight matrices into Wt[mat][n][k] fp16
// (dual-dtype source) so GEMM B-fragment loads are contiguous 16B.
// ---------------------------------------------------------------------------
__global__ void prep_w(const void* __restrict__ wq, const void* __restrict__ wk,
                       const void* __restrict__ wv,
                       const unsigned int* __restrict__ flag,
                       _Float16* __restrict__ Wt)
{
    const bool f32 = (*flag != 0u);
    int i = blockIdx.x * 256 + threadIdx.x;
    const int per = CDIM * HD;               // 24576
    if (i >= 3 * per) return;
    int mat = i / per;
    int rem = i - mat * per;
    int k = rem / HD;
    int n = rem - k * HD;
    const void* w = (mat == 0) ? wq : ((mat == 1) ? wk : wv);
    float v = f32 ? ((const float*)w)[rem]
                  : bf2f(((const unsigned short*)w)[rem]);
    Wt[((size_t)mat * HD + n) * CDIM + k] = (_Float16)v;
}

// ---------------------------------------------------------------------------
// Kernel C: QKV projection GEMM for batches [b0, b0+nb), fused bias + RoPE.
// Block = 256 threads (4 waves), tile 64 rows x 64 cols, wave = 16 rows.
// mfma_f32_16x16x32_f16: A[m=lane&15][k=quad*8+j], B[k=quad*8+j][n=lane&15],
// C/D[row=quad*4+reg][col=lane&15]. RoPE (fres==1 -> angle=t): even/odd cols
// are adjacent lanes -> shfl_xor 1. Q,K (local b,t,d) fp16; V transposed
// (local b,d,t) fp16.
// ---------------------------------------------------------------------------
__global__ __launch_bounds__(256) void qkv_gemm(
    const void* __restrict__ xv, const _Float16* __restrict__ Wt,
    const void* __restrict__ bqv, const void* __restrict__ bkv,
    const void* __restrict__ bvv, const unsigned int* __restrict__ flag,
    _Float16* __restrict__ Qw, _Float16* __restrict__ Kw,
    _Float16* __restrict__ Vtw, int b0)
{
    const bool f32 = (*flag != 0u);
    const int mtile = blockIdx.x;
    const int mat   = blockIdx.y;
    const int tid   = threadIdx.x;
    const int wave  = tid >> 6;
    const int lane  = tid & 63;
    const int l16   = lane & 15;
    const int quad  = lane >> 4;

    const int row0 = mtile * 64 + wave * 16;            // chunk-local row
    const _Float16* W = Wt + (size_t)mat * CDIM * HD;   // [n][k]

    floatx4 acc[4];
#pragma unroll
    for (int s4 = 0; s4 < 4; ++s4)
#pragma unroll
        for (int r = 0; r < 4; ++r) acc[s4][r] = 0.f;

    // global element index of this lane's A-row slice
    const size_t arow = ((size_t)b0 * TSEQ + row0 + l16) * CDIM + quad * 8;

#pragma unroll 4
    for (int kk = 0; kk < CDIM; kk += 32) {
        half8 a;
        if (!f32) {
            uint4 araw = *(const uint4*)((const unsigned short*)xv + arow + kk);
            const unsigned short* ar = (const unsigned short*)&araw;
#pragma unroll
            for (int jj = 0; jj < 8; ++jj) a[jj] = (_Float16)bf2f(ar[jj]);
        } else {
            const float* xf = (const float*)xv + arow + kk;
            float4 a0 = *(const float4*)(xf);
            float4 a1 = *(const float4*)(xf + 4);
            a[0] = (_Float16)a0.x; a[1] = (_Float16)a0.y;
            a[2] = (_Float16)a0.z; a[3] = (_Float16)a0.w;
            a[4] = (_Float16)a1.x; a[5] = (_Float16)a1.y;
            a[6] = (_Float16)a1.z; a[7] = (_Float16)a1.w;
        }
#pragma unroll
        for (int s4 = 0; s4 < 4; ++s4) {
            half8 bb = *(const half8*)(W + (size_t)(s4 * 16 + l16) * CDIM + kk + quad * 8);
            acc[s4] = __builtin_amdgcn_mfma_f32_16x16x32_f16(a, bb, acc[s4], 0, 0, 0);
        }
    }

    const void* biasv = (mat == 0) ? bqv : ((mat == 1) ? bkv : bvv);
    float bvals[4];
#pragma unroll
    for (int s4 = 0; s4 < 4; ++s4) {
        const int c = s4 * 16 + l16;
        bvals[s4] = f32 ? ((const float*)biasv)[c]
                        : bf2f(((const unsigned short*)biasv)[c]);
    }

    const int t0 = row0 & (TSEQ - 1);   // local t (chunk rows are whole batches)

    if (mat < 2) {
        _Float16* dst = (mat == 0) ? Qw : Kw;
#pragma unroll
        for (int r = 0; r < 4; ++r) {
            const int t = t0 + quad * 4 + r;
            const float st = sinf((float)t);
            const float ct = cosf((float)t);
            const int row = row0 + quad * 4 + r;
#pragma unroll
            for (int s4 = 0; s4 < 4; ++s4) {
                const int c = s4 * 16 + l16;
                float v = acc[s4][r] + bvals[s4];
                float p = __shfl_xor(v, 1);
                v = (c & 1) ? (p * st + v * ct) : (v * ct - p * st);
                dst[(size_t)row * HD + c] = (_Float16)v;
            }
        }
    } else {
#pragma unroll
        for (int r = 0; r < 4; ++r) {
            const int row  = row0 + quad * 4 + r;
            const int bidx = row >> 9;             // local batch
            const int t    = row & (TSEQ - 1);
#pragma unroll
            for (int s4 = 0; s4 < 4; ++s4) {
                const int c = s4 * 16 + l16;
                float v = acc[s4][r] + bvals[s4];
                Vtw[((size_t)bidx * HD + c) * TSEQ + t] = (_Float16)v;
            }
        }
    }
}

// ---------------------------------------------------------------------------
// Kernel D: causal flash attention for batches [b0, b0+nb). Block = (local b,
// q-tile of 64), 4 waves, wave owns 16 q-rows. Online softmax; P goes
// C-layout -> LDS -> A-layout. Output fp32 (reference output dtype).
// ---------------------------------------------------------------------------
__global__ __launch_bounds__(256) void attn_kernel(
    const _Float16* __restrict__ Qw, const _Float16* __restrict__ Kw,
    const _Float16* __restrict__ Vtw, float* __restrict__ out, int b0)
{
    const int bl   = blockIdx.x;                 // local batch
    const int qt   = blockIdx.y;
    const int tid  = threadIdx.x;
    const int wave = tid >> 6;
    const int lane = tid & 63;
    const int l16  = lane & 15;
    const int quad = lane >> 4;

    // stride 72 halfs = 144B: rows stay 16B-aligned, 2-way max bank aliasing
    __shared__ __align__(16) _Float16 pbuf[4][16][72];

    const _Float16* Qb = Qw  + (size_t)bl * TSEQ * HD;
    const _Float16* Kb = Kw  + (size_t)bl * TSEQ * HD;
    const _Float16* Vb = Vtw + (size_t)bl * HD * TSEQ;   // [d][t]

    const int qr0 = qt * 64 + wave * 16;

    half8 aQ0 = *(const half8*)(Qb + (size_t)(qr0 + l16) * HD + quad * 8);
    half8 aQ1 = *(const half8*)(Qb + (size_t)(qr0 + l16) * HD + 32 + quad * 8);

    floatx4 accO[4];
    float m_i[4], l_i[4];
#pragma unroll
    for (int s4 = 0; s4 < 4; ++s4)
#pragma unroll
        for (int r = 0; r < 4; ++r) accO[s4][r] = 0.f;
#pragma unroll
    for (int r = 0; r < 4; ++r) { m_i[r] = -30000.f; l_i[r] = 0.f; }

    const float scale = 0.051031036307982884f;   // 384^-0.5

    for (int j = 0; j <= qt; ++j) {
        const int kb = j * 64;

        floatx4 s[4];
#pragma unroll
        for (int s4 = 0; s4 < 4; ++s4) {
#pragma unroll
            for (int r = 0; r < 4; ++r) s[s4][r] = 0.f;
            const _Float16* kp = Kb + (size_t)(kb + s4 * 16 + l16) * HD + quad * 8;
            half8 bK0 = *(const half8*)(kp);
            half8 bK1 = *(const half8*)(kp + 32);
            s[s4] = __builtin_amdgcn_mfma_f32_16x16x32_f16(aQ0, bK0, s[s4], 0, 0, 0);
            s[s4] = __builtin_amdgcn_mfma_f32_16x16x32_f16(aQ1, bK1, s[s4], 0, 0, 0);
        }

        float sv[4][4];
        float tmax[4] = {-30000.f, -30000.f, -30000.f, -30000.f};
#pragma unroll
        for (int s4 = 0; s4 < 4; ++s4) {
            const int kcol = kb + s4 * 16 + l16;
#pragma unroll
            for (int r = 0; r < 4; ++r) {
                float v = s[s4][r] * scale;
                const int qrow = qr0 + quad * 4 + r;
                if (kcol > qrow) v = -30000.f;
                sv[s4][r] = v;
                tmax[r] = fmaxf(tmax[r], v);
            }
        }
#pragma unroll
        for (int r = 0; r < 4; ++r)
#pragma unroll
            for (int off = 1; off < 16; off <<= 1)
                tmax[r] = fmaxf(tmax[r], __shfl_xor(tmax[r], off));

        float alpha[4], rs[4];
#pragma unroll
        for (int r = 0; r < 4; ++r) {
            const float mnew = fmaxf(m_i[r], tmax[r]);
            alpha[r] = __expf(m_i[r] - mnew);
            m_i[r] = mnew;
            rs[r] = 0.f;
        }
        float pv[4][4];
#pragma unroll
        for (int s4 = 0; s4 < 4; ++s4)
#pragma unroll
            for (int r = 0; r < 4; ++r) {
                const float p = __expf(sv[s4][r] - m_i[r]);
                pv[s4][r] = p;
                rs[r] += p;
            }
#pragma unroll
        for (int r = 0; r < 4; ++r) {
#pragma unroll
            for (int off = 1; off < 16; off <<= 1)
                rs[r] += __shfl_xor(rs[r], off);
            l_i[r] = l_i[r] * alpha[r] + rs[r];
        }
#pragma unroll
        for (int s4 = 0; s4 < 4; ++s4)
#pragma unroll
            for (int r = 0; r < 4; ++r) accO[s4][r] *= alpha[r];

        __syncthreads();
#pragma unroll
        for (int s4 = 0; s4 < 4; ++s4)
#pragma unroll
            for (int r = 0; r < 4; ++r)
                pbuf[wave][quad * 4 + r][s4 * 16 + l16] = (_Float16)pv[s4][r];
        __syncthreads();

        half8 aP0 = *(const half8*)(&pbuf[wave][l16][quad * 8]);
        half8 aP1 = *(const half8*)(&pbuf[wave][l16][32 + quad * 8]);

#pragma unroll
        for (int s4 = 0; s4 < 4; ++s4) {
            const _Float16* vp = Vb + (size_t)(s4 * 16 + l16) * TSEQ + kb + quad * 8;
            half8 bV0 = *(const half8*)(vp);
            half8 bV1 = *(const half8*)(vp + 32);
            accO[s4] = __builtin_amdgcn_mfma_f32_16x16x32_f16(aP0, bV0, accO[s4], 0, 0, 0);
            accO[s4] = __builtin_amdgcn_mfma_f32_16x16x32_f16(aP1, bV1, accO[s4], 0, 0, 0);
        }
    }

    float inv[4];
#pragma unroll
    for (int r = 0; r < 4; ++r) inv[r] = 1.f / l_i[r];
#pragma unroll
    for (int s4 = 0; s4 < 4; ++s4) {
        const int dcol = s4 * 16 + l16;
#pragma unroll
        for (int r = 0; r < 4; ++r) {
            const int qrow = qr0 + quad * 4 + r;
            out[((size_t)(b0 + bl) * TSEQ + qrow) * HD + dcol] =
                accO[s4][r] * inv[r];                 // fp32 store
        }
    }
}

// ---------------------------------------------------------------------------
extern "C" void kernel_launch(void* const* d_in, const int* in_sizes, int n_in,
                              void* d_out, int out_size, void* d_ws, size_t ws_size,
                              hipStream_t stream)
{
    char* ws = (char*)d_ws;
    unsigned int* flag = (unsigned int*)ws;                 // 256 B reserved
    _Float16* Wt = (_Float16*)(ws + 256);                   // 147456 B
    char* qkv_base = ws + 256 + 147456;                     // 147712 (16B-mult)

    // size the batch chunk to the workspace we actually have
    const size_t per_b = (size_t)3 * TSEQ * HD * sizeof(_Float16);  // 196608 B
    size_t avail = (ws_size > (size_t)147712) ? ws_size - 147712 : per_b;
    int nbc = (int)(avail / per_b);
    if (nbc > NB) nbc = NB;
    if (nbc < 1)  nbc = 1;

    const size_t chunk_elems = (size_t)nbc * TSEQ * HD;
    _Float16* Qw  = (_Float16*)qkv_base;
    _Float16* Kw  = Qw + chunk_elems;
    _Float16* Vtw = Kw + chunk_elems;

    detect_dtype<<<dim3(1), dim3(256), 0, stream>>>(
        (const unsigned short*)d_in[0], flag);
    prep_w<<<dim3((3 * CDIM * HD + 255) / 256), dim3(256), 0, stream>>>(
        d_in[1], d_in[3], d_in[5], flag, Wt);

    for (int b0 = 0; b0 < NB; b0 += nbc) {
        const int nb = (NB - b0 < nbc) ? (NB - b0) : nbc;
        qkv_gemm<<<dim3(nb * 8, 3), dim3(256), 0, stream>>>(
            d_in[0], Wt, d_in[2], d_in[4], d_in[6], flag, Qw, Kw, Vtw, b0);
        attn_kernel<<<dim3(nb, 8), dim3(256), 0, stream>>>(
            Qw, Kw, Vtw, (float*)d_out, b0);
    }
}